// Round 1
// baseline (1207.601 us; speedup 1.0000x reference)
//
#include <hip/hip_runtime.h>
#include <hip/hip_bf16.h>
#include <math.h>

#define BB   2
#define NN   2048
#define KK   32
#define HH   128
#define DFF  512
#define CE   39
#define LDK  36      // padded leading dim for [C][K] LDS tiles: 36*4B = 144B, 16B-aligned
#define EPSF 1e-6f

// ---------------- helpers ----------------

__device__ __forceinline__ float sgnf(float x) {
    return (x > 0.f) ? 1.f : ((x < 0.f) ? -1.f : 0.f);
}

// block of 128 threads; returns sum over all threads (broadcast)
__device__ __forceinline__ float block_reduce_sum128(float v, float* red, int tid) {
    red[tid] = v; __syncthreads();
    if (tid < 64) red[tid] += red[tid + 64]; __syncthreads();
    if (tid < 32) red[tid] += red[tid + 32]; __syncthreads();
    if (tid < 16) red[tid] += red[tid + 16]; __syncthreads();
    if (tid < 8)  red[tid] += red[tid + 8];  __syncthreads();
    if (tid < 4)  red[tid] += red[tid + 4];  __syncthreads();
    if (tid < 2)  red[tid] += red[tid + 2];  __syncthreads();
    if (tid < 1)  red[tid] += red[tid + 1];  __syncthreads();
    float r = red[0]; __syncthreads();
    return r;
}

__device__ __forceinline__ void norm3(float& x, float& y, float& z) {
    float n = sqrtf(x * x + y * y + z * z);
    n = fmaxf(n, 1e-12f);
    x /= n; y /= n; z /= n;
}

// ---------------- kNN: top-32 smallest masked distances per row ----------------

__global__ __launch_bounds__(256) void knn_kernel(const float* __restrict__ X,
                                                  const float* __restrict__ mask,
                                                  int* __restrict__ E_idx,
                                                  float* __restrict__ D_nb) {
    __shared__ float Xs[NN * 3];
    __shared__ float Ds[NN];
    __shared__ float red_v[256];
    __shared__ int   red_i[256];

    int bid = blockIdx.x;
    int b = bid / NN, n = bid % NN;
    int tid = threadIdx.x;
    const float* Xb = X + (size_t)b * NN * 3;

    for (int i = tid; i < NN * 3; i += 256) Xs[i] = Xb[i];
    __syncthreads();

    float xn0 = Xs[n * 3], xn1 = Xs[n * 3 + 1], xn2 = Xs[n * 3 + 2];
    float mn = mask[b * NN + n];

    float lmax = -1e30f;
    for (int j = tid; j < NN; j += 256) {
        float dx = Xs[j * 3] - xn0, dy = Xs[j * 3 + 1] - xn1, dz = Xs[j * 3 + 2] - xn2;
        float d = sqrtf(dx * dx + dy * dy + dz * dz + EPSF);
        float m2 = mn * mask[b * NN + j];
        float Dv = m2 * d;
        Ds[j] = Dv;
        lmax = fmaxf(lmax, Dv);
    }
    red_v[tid] = lmax; __syncthreads();
    for (int s = 128; s > 0; s >>= 1) {
        if (tid < s) red_v[tid] = fmaxf(red_v[tid], red_v[tid + s]);
        __syncthreads();
    }
    float Dmax = red_v[0];
    __syncthreads();
    for (int j = tid; j < NN; j += 256) {
        float m2 = mn * mask[b * NN + j];
        Ds[j] += (1.0f - m2) * Dmax;
    }
    __syncthreads();

    for (int s = 0; s < KK; s++) {
        float bv = 1e30f; int bi = -1;
        for (int j = tid; j < NN; j += 256) {
            float v = Ds[j];
            if (v < bv || (v == bv && j < bi)) { bv = v; bi = j; }
        }
        red_v[tid] = bv; red_i[tid] = bi; __syncthreads();
        for (int st = 128; st > 0; st >>= 1) {
            if (tid < st) {
                float v2 = red_v[tid + st]; int i2 = red_i[tid + st];
                if (v2 < red_v[tid] || (v2 == red_v[tid] && i2 < red_i[tid])) {
                    red_v[tid] = v2; red_i[tid] = i2;
                }
            }
            __syncthreads();
        }
        if (tid == 0) {
            int idx = red_i[0];
            E_idx[(size_t)bid * KK + s] = idx;
            D_nb[(size_t)bid * KK + s] = red_v[0];
            Ds[idx] = 1e30f;
        }
        __syncthreads();
    }
}

// ---------------- backbone frames + angle features ----------------

__global__ void orient_kernel(const float* __restrict__ X,
                              float* __restrict__ AD,
                              float* __restrict__ Of) {
    int t = blockIdx.x * blockDim.x + threadIdx.x;
    if (t >= BB * NN) return;
    int b = t / NN, n = t % NN;
    float* ad = AD + (size_t)t * 3;
    float* of = Of + (size_t)t * 9;
    if (n < 1 || n > NN - 3) {
        ad[0] = ad[1] = ad[2] = 0.f;
        #pragma unroll
        for (int i = 0; i < 9; i++) of[i] = 0.f;
        return;
    }
    const float* Xb = X + (size_t)b * NN * 3;
    float p0x = Xb[(n - 1) * 3], p0y = Xb[(n - 1) * 3 + 1], p0z = Xb[(n - 1) * 3 + 2];
    float p1x = Xb[n * 3],       p1y = Xb[n * 3 + 1],       p1z = Xb[n * 3 + 2];
    float p2x = Xb[(n + 1) * 3], p2y = Xb[(n + 1) * 3 + 1], p2z = Xb[(n + 1) * 3 + 2];
    float p3x = Xb[(n + 2) * 3], p3y = Xb[(n + 2) * 3 + 1], p3z = Xb[(n + 2) * 3 + 2];

    // U[j] = norm(X[j+1]-X[j]); u2=U[n-1], u1=U[n], u0=U[n+1]
    float u2x = p1x - p0x, u2y = p1y - p0y, u2z = p1z - p0z; norm3(u2x, u2y, u2z);
    float u1x = p2x - p1x, u1y = p2y - p1y, u1z = p2z - p1z; norm3(u1x, u1y, u1z);
    float u0x = p3x - p2x, u0y = p3y - p2y, u0z = p3z - p2z; norm3(u0x, u0y, u0z);

    // n2 = norm(u2 x u1), n1 = norm(u1 x u0)
    float n2x = u2y * u1z - u2z * u1y, n2y = u2z * u1x - u2x * u1z, n2z = u2x * u1y - u2y * u1x;
    norm3(n2x, n2y, n2z);
    float n1x = u1y * u0z - u1z * u0y, n1y = u1z * u0x - u1x * u0z, n1z = u1x * u0y - u1y * u0x;
    norm3(n1x, n1y, n1z);

    float cosA = -(u1x * u0x + u1y * u0y + u1z * u0z);
    cosA = fminf(fmaxf(cosA, -1.f + EPSF), 1.f - EPSF);
    float A = acosf(cosA);
    float cosD = n2x * n1x + n2y * n1y + n2z * n1z;
    cosD = fminf(fmaxf(cosD, -1.f + EPSF), 1.f - EPSF);
    float sg = sgnf(u2x * n1x + u2y * n1y + u2z * n1z);
    float Dih = sg * acosf(cosD);

    ad[0] = cosf(A);
    ad[1] = sinf(A) * cosf(Dih);
    ad[2] = sinf(A) * sinf(Dih);

    // o1 = norm(u2-u1); rows of Om: o1, n2, o1 x n2
    float o1x = u2x - u1x, o1y = u2y - u1y, o1z = u2z - u1z; norm3(o1x, o1y, o1z);
    float cx = o1y * n2z - o1z * n2y, cy = o1z * n2x - o1x * n2z, cz = o1x * n2y - o1y * n2x;
    of[0] = o1x; of[1] = o1y; of[2] = o1z;
    of[3] = n2x; of[4] = n2y; of[5] = n2z;
    of[6] = cx;  of[7] = cy;  of[8] = cz;
}

// ---------------- node features: V = LN(AD@Wn+bn); h_V = V@Wv+bv ----------------

__global__ __launch_bounds__(128) void node_feat_kernel(const float* __restrict__ AD,
                                                        const float* __restrict__ Wn,
                                                        const float* __restrict__ bn,
                                                        const float* __restrict__ gn,
                                                        const float* __restrict__ hn,
                                                        const float* __restrict__ Wv,
                                                        const float* __restrict__ bv,
                                                        float* __restrict__ hV) {
    __shared__ float y[HH];
    __shared__ float red[HH];
    int n = blockIdx.x; int h = threadIdx.x;
    float a0 = AD[n * 3], a1 = AD[n * 3 + 1], a2 = AD[n * 3 + 2];
    float v = bn[h] + a0 * Wn[h] + a1 * Wn[HH + h] + a2 * Wn[2 * HH + h];
    float mu = block_reduce_sum128(v, red, h) * (1.f / HH);
    float d = v - mu;
    float var = block_reduce_sum128(d * d, red, h) * (1.f / (HH - 1));
    float sig = sqrtf(var + EPSF);
    float yv = gn[h] * d / (sig + EPSF) + hn[h];
    y[h] = yv; __syncthreads();
    float acc = bv[h];
    for (int c = 0; c < HH; c++) acc += y[c] * Wv[c * HH + h];
    hV[(size_t)n * HH + h] = acc;
}

// ---------------- edge features: E=LN(feat@We+be); h_E=E@Wq+bq ----------------
// one block per (b,n); 128 threads = output channels; K=32 edges batched in registers

__global__ __launch_bounds__(128) void edge_feat_kernel(const float* __restrict__ X,
                                                        const int* __restrict__ E_idx,
                                                        const float* __restrict__ D_nb,
                                                        const float* __restrict__ Of,
                                                        const float* __restrict__ We,
                                                        const float* __restrict__ be,
                                                        const float* __restrict__ ge,
                                                        const float* __restrict__ he,
                                                        const float* __restrict__ Wq,
                                                        const float* __restrict__ bq,
                                                        float* __restrict__ hE) {
    __shared__ float ef[CE * LDK];
    __shared__ float lM[HH * LDK];
    __shared__ float mu_s[KK], sg_s[KK];

    int bid = blockIdx.x; int b = bid / NN, n = bid % NN; int tid = threadIdx.x;

    if (tid < KK) {
        int k = tid;
        int e = E_idx[(size_t)bid * KK + k];
        float dpos = (float)e - (float)n;
        #pragma unroll
        for (int p = 0; p < 8; p++) {
            float fr = expf((float)(2 * p) * -0.5756462732485115f); // -ln(10000)/16
            float ang = dpos * fr;
            ef[p * LDK + k] = cosf(ang);
            ef[(8 + p) * LDK + k] = sinf(ang);
        }
        float Dv = D_nb[(size_t)bid * KK + k];
        #pragma unroll
        for (int i = 0; i < 16; i++) {
            float m = (20.f / 15.f) * (float)i;
            float z = (Dv - m) * 0.8f;
            ef[(16 + i) * LDK + k] = expf(-z * z);
        }
        const float* Omp = Of + (size_t)(b * NN + n) * 9;
        const float* Onp = Of + (size_t)(b * NN + e) * 9;
        float Om[9], On[9];
        #pragma unroll
        for (int i = 0; i < 9; i++) { Om[i] = Omp[i]; On[i] = Onp[i]; }
        float vx = X[(size_t)(b * NN + e) * 3 + 0] - X[(size_t)(b * NN + n) * 3 + 0];
        float vy = X[(size_t)(b * NN + e) * 3 + 1] - X[(size_t)(b * NN + n) * 3 + 1];
        float vz = X[(size_t)(b * NN + e) * 3 + 2] - X[(size_t)(b * NN + n) * 3 + 2];
        float t0 = Om[0] * vx + Om[1] * vy + Om[2] * vz;
        float t1 = Om[3] * vx + Om[4] * vy + Om[5] * vz;
        float t2 = Om[6] * vx + Om[7] * vy + Om[8] * vz;
        float nr = fmaxf(sqrtf(t0 * t0 + t1 * t1 + t2 * t2), 1e-12f);
        ef[32 * LDK + k] = t0 / nr; ef[33 * LDK + k] = t1 / nr; ef[34 * LDK + k] = t2 / nr;
        // R = Om^T @ On : R[i][l] = sum_j Om[j][i]*On[j][l]
        float R[9];
        #pragma unroll
        for (int i = 0; i < 3; i++)
            #pragma unroll
            for (int l = 0; l < 3; l++)
                R[i * 3 + l] = Om[0 + i] * On[0 + l] + Om[3 + i] * On[3 + l] + Om[6 + i] * On[6 + l];
        float Rxx = R[0], Ryy = R[4], Rzz = R[8];
        float mx = 0.5f * sqrtf(fabsf(1.f + Rxx - Ryy - Rzz));
        float my = 0.5f * sqrtf(fabsf(1.f - Rxx + Ryy - Rzz));
        float mz = 0.5f * sqrtf(fabsf(1.f - Rxx - Ryy + Rzz));
        float qx = sgnf(R[2 * 3 + 1] - R[1 * 3 + 2]) * mx;
        float qy = sgnf(R[0 * 3 + 2] - R[2 * 3 + 0]) * my;
        float qz = sgnf(R[1 * 3 + 0] - R[0 * 3 + 1]) * mz;
        float qw = 0.5f * sqrtf(fmaxf(1.f + Rxx + Ryy + Rzz, 0.f));
        float qn = fmaxf(sqrtf(qx * qx + qy * qy + qz * qz + qw * qw), 1e-12f);
        ef[35 * LDK + k] = qx / qn; ef[36 * LDK + k] = qy / qn;
        ef[37 * LDK + k] = qz / qn; ef[38 * LDK + k] = qw / qn;
    }
    __syncthreads();

    // GEMM1: (39 -> 128) for 32 edges, accumulators in registers
    float acc[KK];
    float bbe = be[tid];
    #pragma unroll
    for (int k = 0; k < KK; k++) acc[k] = bbe;
    for (int c = 0; c < CE; c++) {
        float w = We[c * HH + tid];
        #pragma unroll
        for (int k = 0; k < KK; k++) acc[k] += ef[c * LDK + k] * w;
    }
    #pragma unroll
    for (int k = 0; k < KK; k++) lM[tid * LDK + k] = acc[k];
    __syncthreads();

    if (tid < KK) {  // per-edge LN stats over 128 channels
        float ssum = 0.f;
        for (int c = 0; c < HH; c++) ssum += lM[c * LDK + tid];
        float mu = ssum * (1.f / HH);
        float ss = 0.f;
        for (int c = 0; c < HH; c++) { float dd = lM[c * LDK + tid] - mu; ss += dd * dd; }
        mu_s[tid] = mu;
        sg_s[tid] = sqrtf(ss * (1.f / (HH - 1)) + EPSF);
    }
    __syncthreads();

    float g = ge[tid], bb = he[tid];
    #pragma unroll
    for (int k = 0; k < KK; k++) {
        float yv = g * (acc[k] - mu_s[k]) / (sg_s[k] + EPSF) + bb;
        lM[tid * LDK + k] = yv;
    }
    __syncthreads();

    // GEMM2: (128 -> 128)
    float acc2[KK];
    float bqh = bq[tid];
    #pragma unroll
    for (int k = 0; k < KK; k++) acc2[k] = bqh;
    for (int c = 0; c < HH; c++) {
        float w = Wq[c * HH + tid];
        #pragma unroll
        for (int k = 0; k < KK; k++) acc2[k] += lM[c * LDK + k] * w;
    }
    float* outp = hE + (size_t)bid * KK * HH;
    #pragma unroll
    for (int k = 0; k < KK; k++) outp[k * HH + tid] = acc2[k];
}

// ---------------- per-layer: P = hV@W1a + b1 ; Q = hV@W1c ----------------

__global__ __launch_bounds__(128) void premix_kernel(const float* __restrict__ hV,
                                                     const float* __restrict__ W1,
                                                     const float* __restrict__ b1,
                                                     float* __restrict__ P,
                                                     float* __restrict__ Q) {
    __shared__ float v[HH];
    int n = blockIdx.x; int h = threadIdx.x;
    v[h] = hV[(size_t)n * HH + h]; __syncthreads();
    float p = b1[h], q = 0.f;
    for (int c = 0; c < HH; c++) {
        float x = v[c];
        p += x * W1[c * HH + h];
        q += x * W1[(256 + c) * HH + h];
    }
    P[(size_t)n * HH + h] = p;
    Q[(size_t)n * HH + h] = q;
}

// ---------------- per-layer main: msgs, K-sum, LN, FFN, LN ----------------

__global__ __launch_bounds__(128) void layer_kernel(const float* __restrict__ mask,
                                                    const int* __restrict__ E_idx,
                                                    const float* __restrict__ hE,
                                                    const float* __restrict__ P,
                                                    const float* __restrict__ Q,
                                                    const float* __restrict__ W1,
                                                    const float* __restrict__ W2,
                                                    const float* __restrict__ b2,
                                                    const float* __restrict__ W3,
                                                    const float* __restrict__ b3,
                                                    const float* __restrict__ Wi,
                                                    const float* __restrict__ bi,
                                                    const float* __restrict__ Wo,
                                                    const float* __restrict__ bo,
                                                    const float* __restrict__ g0,
                                                    const float* __restrict__ h0,
                                                    const float* __restrict__ g1,
                                                    const float* __restrict__ h1,
                                                    float* __restrict__ hV) {
    __shared__ float lE[HH * LDK];
    __shared__ float sv[HH];
    __shared__ float hid[DFF];
    __shared__ float red[HH];
    __shared__ float matt_s[KK];
    __shared__ int   eix[KK];

    int bid = blockIdx.x;
    int b = bid / NN, n = bid % NN;
    int h = threadIdx.x;

    if (h < KK) {
        int e = E_idx[(size_t)bid * KK + h];
        eix[h] = e;
        matt_s[h] = mask[b * NN + n] * mask[b * NN + e];
    }
    __syncthreads();

    // stage h_E[n,k,:] into LDS transposed [c][k]
    const float* hEb = hE + (size_t)bid * KK * HH;
    #pragma unroll
    for (int k = 0; k < KK; k++) lE[h * LDK + k] = hEb[k * HH + h];

    float Ph = P[(size_t)bid * HH + h];
    float acc[KK];
    #pragma unroll
    for (int k = 0; k < KK; k++) acc[k] = Ph + Q[((size_t)b * NN + eix[k]) * HH + h];
    __syncthreads();

    // stage A: += h_E @ W1b
    const float* W1b = W1 + 128 * HH;
    for (int c = 0; c < HH; c++) {
        float w = W1b[c * HH + h];
        #pragma unroll
        for (int k = 0; k < KK; k++) acc[k] += lE[c * LDK + k] * w;
    }
    #pragma unroll
    for (int k = 0; k < KK; k++) acc[k] = fmaxf(acc[k], 0.f);
    __syncthreads();
    #pragma unroll
    for (int k = 0; k < KK; k++) lE[h * LDK + k] = acc[k];
    __syncthreads();

    // stage B: m2 = relu(m1 @ W2 + b2)
    float acc2[KK];
    float bb2 = b2[h];
    #pragma unroll
    for (int k = 0; k < KK; k++) acc2[k] = bb2;
    for (int c = 0; c < HH; c++) {
        float w = W2[c * HH + h];
        #pragma unroll
        for (int k = 0; k < KK; k++) acc2[k] += lE[c * LDK + k] * w;
    }

    // weighted K-sum (W3 is linear -> applied after the sum)
    float s = 0.f, cnt = 0.f;
    #pragma unroll
    for (int k = 0; k < KK; k++) {
        float m = matt_s[k];
        s += fmaxf(acc2[k], 0.f) * m;
        cnt += m;
    }
    sv[h] = s; __syncthreads();

    float t = cnt * b3[h];
    for (int c = 0; c < HH; c++) t += sv[c] * W3[c * HH + h];
    float r = hV[(size_t)bid * HH + h] + t * (1.f / 30.f);

    // LN0
    float mu = block_reduce_sum128(r, red, h) * (1.f / HH);
    float d = r - mu;
    float var = block_reduce_sum128(d * d, red, h) * (1.f / (HH - 1));
    float sig = sqrtf(var + EPSF);
    float v1 = g0[h] * d / (sig + EPSF) + h0[h];
    __syncthreads();
    sv[h] = v1; __syncthreads();

    // FFN 128 -> 512 -> 128
    #pragma unroll
    for (int m = 0; m < 4; m++) {
        int j = h + 128 * m;
        float a = bi[j];
        for (int c = 0; c < HH; c++) a += sv[c] * Wi[c * DFF + j];
        hid[j] = fmaxf(a, 0.f);
    }
    __syncthreads();
    float o = bo[h];
    for (int j = 0; j < DFF; j++) o += hid[j] * Wo[j * HH + h];
    float r2 = v1 + o;

    // LN1
    mu = block_reduce_sum128(r2, red, h) * (1.f / HH);
    d = r2 - mu;
    var = block_reduce_sum128(d * d, red, h) * (1.f / (HH - 1));
    sig = sqrtf(var + EPSF);
    float y = g1[h] * d / (sig + EPSF) + h1[h];
    y *= mask[b * NN + n];
    hV[(size_t)bid * HH + h] = y;
}

__global__ void copy_kernel(const float* __restrict__ s, float* __restrict__ d, int n) {
    int i = blockIdx.x * 256 + threadIdx.x;
    if (i < n) d[i] = s[i];
}

// ---------------- launch ----------------

extern "C" void kernel_launch(void* const* d_in, const int* in_sizes, int n_in,
                              void* d_out, int out_size, void* d_ws, size_t ws_size,
                              hipStream_t stream) {
    const float* X    = (const float*)d_in[0];
    const float* mask = (const float*)d_in[1];
    const float* Wn   = (const float*)d_in[2];
    const float* bn   = (const float*)d_in[3];
    const float* gn   = (const float*)d_in[4];
    const float* hn   = (const float*)d_in[5];
    const float* We   = (const float*)d_in[6];
    const float* be   = (const float*)d_in[7];
    const float* ge   = (const float*)d_in[8];
    const float* he   = (const float*)d_in[9];
    const float* Wv   = (const float*)d_in[10];
    const float* bv   = (const float*)d_in[11];
    const float* Wq   = (const float*)d_in[12];
    const float* bq   = (const float*)d_in[13];
    const float* lW1  = (const float*)d_in[14];
    const float* lb1  = (const float*)d_in[15];
    const float* lW2  = (const float*)d_in[16];
    const float* lb2  = (const float*)d_in[17];
    const float* lW3  = (const float*)d_in[18];
    const float* lb3  = (const float*)d_in[19];
    const float* lWi  = (const float*)d_in[20];
    const float* lbi  = (const float*)d_in[21];
    const float* lWo  = (const float*)d_in[22];
    const float* lbo  = (const float*)d_in[23];
    const float* lg0  = (const float*)d_in[24];
    const float* lh0  = (const float*)d_in[25];
    const float* lg1  = (const float*)d_in[26];
    const float* lh1  = (const float*)d_in[27];

    char* ws = (char*)d_ws;
    size_t off = 0;
    auto alloc = [&](size_t nfloats) { void* p = ws + off; off += nfloats * 4; return p; };
    int*   E_idx = (int*)  alloc((size_t)BB * NN * KK);
    float* D_nb  = (float*)alloc((size_t)BB * NN * KK);
    float* ADb   = (float*)alloc((size_t)BB * NN * 3);
    float* Ofb   = (float*)alloc((size_t)BB * NN * 9);
    float* hV    = (float*)alloc((size_t)BB * NN * HH);
    float* hE    = (float*)alloc((size_t)BB * NN * KK * HH);
    float* Pb    = (float*)alloc((size_t)BB * NN * HH);
    float* Qb    = (float*)alloc((size_t)BB * NN * HH);
    if (off > ws_size) return;  // workspace too small; fail loudly via validation

    knn_kernel<<<BB * NN, 256, 0, stream>>>(X, mask, E_idx, D_nb);
    orient_kernel<<<(BB * NN + 255) / 256, 256, 0, stream>>>(X, ADb, Ofb);
    node_feat_kernel<<<BB * NN, HH, 0, stream>>>(ADb, Wn, bn, gn, hn, Wv, bv, hV);
    edge_feat_kernel<<<BB * NN, HH, 0, stream>>>(X, E_idx, D_nb, Ofb, We, be, ge, he, Wq, bq, hE);

    for (int l = 0; l < 3; l++) {
        premix_kernel<<<BB * NN, HH, 0, stream>>>(hV, lW1 + (size_t)l * 384 * HH,
                                                  lb1 + (size_t)l * HH, Pb, Qb);
        layer_kernel<<<BB * NN, HH, 0, stream>>>(
            mask, E_idx, hE, Pb, Qb,
            lW1 + (size_t)l * 384 * HH,
            lW2 + (size_t)l * HH * HH, lb2 + (size_t)l * HH,
            lW3 + (size_t)l * HH * HH, lb3 + (size_t)l * HH,
            lWi + (size_t)l * HH * DFF, lbi + (size_t)l * DFF,
            lWo + (size_t)l * DFF * HH, lbo + (size_t)l * HH,
            lg0 + (size_t)l * HH, lh0 + (size_t)l * HH,
            lg1 + (size_t)l * HH, lh1 + (size_t)l * HH,
            hV);
    }
    copy_kernel<<<(BB * NN * HH + 255) / 256, 256, 0, stream>>>(hV, (float*)d_out, BB * NN * HH);
}